// Round 15
// baseline (411.308 us; speedup 1.0000x reference)
//
#include <hip/hip_runtime.h>
#include <hip/hip_bf16.h>
#include <math.h>

#define NEGINF (-INFINITY)

typedef float f32x4 __attribute__((ext_vector_type(4)));

__device__ __forceinline__ float wave_max_f(float m) {
#pragma unroll
  for (int d = 32; d > 0; d >>= 1) m = fmaxf(m, __shfl_xor(m, d, 64));
  return m;
}
__device__ __forceinline__ float wave_sum_f(float s) {
#pragma unroll
  for (int d = 32; d > 0; d >>= 1) s += __shfl_xor(s, d, 64);
  return s;
}
__device__ __forceinline__ int wave_sum_i(int s) {
#pragma unroll
  for (int d = 32; d > 0; d >>= 1) s += __shfl_xor(s, d, 64);
  return s;
}

// Whole-wave shift-right-by-1 via DPP (pure VALU). Lane l gets lane l-1's
// value; lane 0 gets 0 (caller overrides).
__device__ __forceinline__ float dpp_wave_shr1(float x) {
  int r = __builtin_amdgcn_mov_dpp(__float_as_int(x), 0x138, 0xf, 0xf, true);
  return __int_as_float(r);
}

// ---------------------------------------------------------------------------
// Kernel A: per (b,t) row of ctc_out[V]: logsumexp, then PRE-GATHER into the
// per-lane layout kB consumes directly:
//   lpsQuad[(b*TPAD + t)*256 + lane*4 + c] = lp(label j(lane,c)), where
//     j(lane,c) = (i_s - 1)>>1, i_s = 7*lane + 2c + (lane even ? 1 : 0)
//   blankArr[b*TPAD + t] = lp(blank)
// So in kB, state s of lane l needs lps = ((l+s)&1) ? quad[s>>1] : blank.
// ---------------------------------------------------------------------------
__global__ __launch_bounds__(256) void kA_lse_gather(
    const float* __restrict__ ctc_out, const int* __restrict__ ctc_label,
    float* __restrict__ lpsQuad, float* __restrict__ blankArr,
    int B, int T, int V, int L, int TPAD)
{
  extern __shared__ float shrow[];  // V floats
  __shared__ float wred[4];
  int row = blockIdx.x;             // b*T + t
  int b = row / T;
  int t = row - b * T;
  int tid = threadIdx.x;
  int w = tid >> 6;
  const float* x = ctc_out + (size_t)row * V;

  float m = NEGINF;
  int nf4 = V >> 2;
  for (int k = tid; k < nf4; k += 256) {
    float4 v = reinterpret_cast<const float4*>(x)[k];
    reinterpret_cast<float4*>(shrow)[k] = v;
    m = fmaxf(m, fmaxf(fmaxf(v.x, v.y), fmaxf(v.z, v.w)));
  }
  for (int k = (nf4 << 2) + tid; k < V; k += 256) {
    float v = x[k]; shrow[k] = v; m = fmaxf(m, v);
  }
  m = wave_max_f(m);
  if ((tid & 63) == 0) wred[w] = m;
  __syncthreads();
  float bm = fmaxf(fmaxf(wred[0], wred[1]), fmaxf(wred[2], wred[3]));
  __syncthreads();

  float s = 0.f;
  for (int k = tid; k < V; k += 256) s += __expf(shrow[k] - bm);
  s = wave_sum_f(s);
  if ((tid & 63) == 0) wred[w] = s;
  __syncthreads();
  float lse = bm + __logf(wred[0] + wred[1] + wred[2] + wred[3]);

  const int* lab = ctc_label + (size_t)b * L;
  float* dq = lpsQuad + ((size_t)b * TPAD + t) * 256;
  {
    int l = tid >> 2, c = tid & 3;
    int i_s = 7 * l + 2 * c + ((l & 1) ? 0 : 1);
    int j = (i_s - 1) >> 1;
    if (j >= L) j = L - 1;
    if (j < 0) j = 0;
    int vi = lab[j];
    if ((unsigned)vi >= (unsigned)V) vi = 0;
    dq[tid] = shrow[vi] - lse;
  }
  if (tid == 0) blankArr[(size_t)b * TPAD + t] = shrow[0] - lse;
}

// ---------------------------------------------------------------------------
// Kernel B: Viterbi forward + backtrace, one wave per batch item.
// 2 time steps per body; per row ONE dwordx4 (per-lane pre-gathered label
// lps) + ONE broadcast dword (blank) - no readlane, no component routing.
// 8-row (4-body) asm ring, vmcnt(12). Single-sided feasibility:
// head blocks (t<L): s<=hi only; tail blocks (t>T-L): s>=lo only; middle:
// none. Offsets packed 14+14 bits per u32 -> LDS; named-scalar backtrace.
// ---------------------------------------------------------------------------
__global__ __launch_bounds__(64, 1) void kB_viterbi(
    const float* __restrict__ lpsQuad, const float* __restrict__ blankArr,
    float* __restrict__ ali, int B, int T, int L, int TPAD)
{
  extern __shared__ float smemf[];   // offrow: (T>>1) u32-rows of 256 B
  const int N = 2 * L + 1;

  int b = blockIdx.x;
  int lane = threadIdx.x;
  const float* lpq = lpsQuad + (size_t)b * TPAD * 256;
  const float* blk = blankArr + (size_t)b * TPAD;

  int i0 = lane * 7;
  float a0v, a1v, a2v, a3v, a4v, a5v, a6v;
  float ainf0, ainf1, ainf2, ainf3, ainf4, ainf5, ainf6;
  {
    const int* lab = (const int*)nullptr;
    (void)lab;
    // two-way flags need labels; recompute from pre-gathered values is not
    // possible, so pass labels via blankArr? No - read ctc_label via lpq?
    // ainf depends only on label equality; compute from lpsQuad row 0 is
    // unsafe (values may coincide). Instead: labels are needed; we read them
    // from the global label array bound through blankArr's tail? Simpler:
    // kA cannot help; read ctc_label directly (bound as extra pointer via
    // blankArr offset is fragile). => labels pointer passed separately.
    // (handled below; this block intentionally empty)
  }
  // NOTE: ainf computed in the launcher-visible way: we receive ctc_label
  // through a second segment appended after blankArr (offset B*TPAD).
  {
    const int* lab2 = (const int*)(blankArr + (size_t)B * TPAD) +
                      (size_t)b * L;
    float ai[7];
#pragma unroll
    for (int s = 0; s < 7; ++s) {
      int i = i0 + s;
      bool valid = (i < N);
      bool odd = (i & 1) != 0;
      int li = (i - 1) >> 1;
      int myl = (odd && valid) ? lab2[li] : 0;
      int pl  = (odd && valid && i >= 3) ? lab2[li - 1] : -1;
      bool two = ((!odd) || (i == 1) || (myl == pl));
      ai[s] = two ? NEGINF : 0.f;   // -inf blocks the p2 path
    }
    ainf0 = ai[0]; ainf1 = ai[1]; ainf2 = ai[2]; ainf3 = ai[3];
    ainf4 = ai[4]; ainf5 = ai[5]; ainf6 = ai[6];
  }
  bool pb0 = ((lane + 0) & 1) != 0;
  bool pb1 = ((lane + 1) & 1) != 0;
  bool pb2 = pb0, pb3 = pb1, pb4 = pb0, pb5 = pb1, pb6 = pb0;

  // t=0 init (plain compiler loads; drained before the asm ring starts).
  {
    f32x4 q00 = *reinterpret_cast<const f32x4*>(lpq + lane * 4);
    float bl00 = blk[0];
    a0v = (i0 == 0) ? bl00 : NEGINF;
    a1v = NEGINF; a2v = NEGINF; a3v = NEGINF; a4v = NEGINF; a5v = NEGINF;
    a6v = NEGINF;
    if (lane == 0) a1v = q00.x;   // state 1 = label 0 (even lane c=0)
  }

  f32x4 rq0, rq1, rq2, rq3, rq4, rq5, rq6, rq7;
  float rb0, rb1, rb2, rb3, rb4, rb5, rb6, rb7;
  unsigned* offu = (unsigned*)smemf;   // rows of 64 u32
  int wix = lane;

  asm volatile("s_waitcnt vmcnt(0) lgkmcnt(0)");
  __builtin_amdgcn_sched_barrier(0);

  unsigned long long baseQ = (unsigned long long)lpq;
  unsigned long long baseB = (unsigned long long)blk;
  unsigned voffQ = (unsigned)(lane * 16) + 1024u;   // row 1
  unsigned voffB = 4u;                              // row 1

#define LOADQ(SL)                                                             \
  asm volatile("global_load_dwordx4 %0, %1, %2"                               \
               : "=v"(rq##SL) : "v"(voffQ), "s"(baseQ));                      \
  voffQ += 1024u;
#define LOADB(SL)                                                             \
  asm volatile("global_load_dword %0, %1, %2"                                 \
               : "=v"(rb##SL) : "v"(voffB), "s"(baseB));                      \
  voffB += 4u;

  // Prologue: rows 1..8 -> slots 0..7 (slot = (row-1)&7). 16 loads.
  LOADQ(0) LOADB(0) LOADQ(1) LOADB(1) LOADQ(2) LOADB(2) LOADQ(3) LOADB(3)
  LOADQ(4) LOADB(4) LOADQ(5) LOADB(5) LOADQ(6) LOADB(6) LOADQ(7) LOADB(7)

  // STEP macros. Args: s, P0, P1, P2, QC (quad comp = q[s>>1]), BL, ND, PK,
  // LO, HI (band bounds; used by STS_LO / STS_HI only).
#define STF(s, P0, P1, P2, QC, BL, ND, PK, LO, HI)                            \
  {                                                                           \
    float q2 = (P2) + ainf##s;                                                \
    float asel = fmaxf(fmaxf((P0), (P1)), q2);                                \
    unsigned t01 = ((P0) > (P1)) ? 0u : 1u;                                   \
    unsigned off = (asel == q2) ? 2u : t01;                                   \
    PK |= off << (2 * (s));                                                   \
    float lps = pb##s ? (QC) : (BL);                                          \
    ND = asel + lps;                                                          \
  }
#define STS_HI(s, P0, P1, P2, QC, BL, ND, PK, LO, HI)                         \
  {                                                                           \
    STF(s, P0, P1, P2, QC, BL, ND, PK, LO, HI)                                \
    ND = ((s) <= (HI)) ? ND : NEGINF;                                         \
  }
#define STS_LO(s, P0, P1, P2, QC, BL, ND, PK, LO, HI)                         \
  {                                                                           \
    STF(s, P0, P1, P2, QC, BL, ND, PK, LO, HI)                                \
    ND = ((s) >= (LO)) ? ND : NEGINF;                                         \
  }

  // One 2-step body. SA/SB = ring slots for rows tt, tt+1.
#define BODY2(SA, SB, M, SM)                                                  \
  {                                                                           \
    const int tt = tt0 + 2 * (M);                                             \
    int lo1 = 2 * (L - T + tt) - i0;                                          \
    int hi1 = 2 * tt - i0;                                                    \
    (void)lo1; (void)hi1;                                                     \
    asm volatile("s_waitcnt vmcnt(12)");                                      \
    __builtin_amdgcn_sched_barrier(0);                                        \
    unsigned packA = 0, packB = 0;                                            \
    float m0, m1, m2, m3, m4, m5, m6;                                         \
    SM(5, a5v, a4v, a3v, rq##SA.z, rb##SA, m5, packA, lo1, hi1)               \
    SM(6, a6v, a5v, a4v, rq##SA.w, rb##SA, m6, packA, lo1, hi1)               \
    float t6m = dpp_wave_shr1(m6);                                            \
    float t5m = dpp_wave_shr1(m5);                                            \
    SM(0, a0v, t6, t5, rq##SA.x, rb##SA, m0, packA, lo1, hi1)                 \
    SM(1, a1v, a0v, t6, rq##SA.x, rb##SA, m1, packA, lo1, hi1)                \
    SM(2, a2v, a1v, a0v, rq##SA.y, rb##SA, m2, packA, lo1, hi1)               \
    SM(3, a3v, a2v, a1v, rq##SA.y, rb##SA, m3, packA, lo1, hi1)               \
    SM(4, a4v, a3v, a2v, rq##SA.z, rb##SA, m4, packA, lo1, hi1)               \
    t6m = (lane == 0) ? NEGINF : t6m;                                         \
    t5m = (lane == 0) ? NEGINF : t5m;                                         \
    float n0, n1, n2, n3, n4, n5, n6;                                         \
    SM(5, m5, m4, m3, rq##SB.z, rb##SB, n5, packB, lo1 + 2, hi1 + 2)          \
    SM(6, m6, m5, m4, rq##SB.w, rb##SB, n6, packB, lo1 + 2, hi1 + 2)          \
    float t6n = dpp_wave_shr1(n6);                                            \
    float t5n = dpp_wave_shr1(n5);                                            \
    SM(0, m0, t6m, t5m, rq##SB.x, rb##SB, n0, packB, lo1 + 2, hi1 + 2)        \
    SM(1, m1, m0, t6m, rq##SB.x, rb##SB, n1, packB, lo1 + 2, hi1 + 2)         \
    SM(2, m2, m1, m0, rq##SB.y, rb##SB, n2, packB, lo1 + 2, hi1 + 2)          \
    SM(3, m3, m2, m1, rq##SB.y, rb##SB, n3, packB, lo1 + 2, hi1 + 2)          \
    SM(4, m4, m3, m2, rq##SB.z, rb##SB, n4, packB, lo1 + 2, hi1 + 2)          \
    offu[wix] = packA | (packB << 14);                                        \
    wix += 64;                                                                \
    LOADQ(SA) LOADB(SA) LOADQ(SB) LOADB(SB)                                   \
    a0v = n0; a1v = n1; a2v = n2; a3v = n3; a4v = n4; a5v = n5; a6v = n6;     \
    t6 = (lane == 0) ? NEGINF : t6n;                                          \
    t5 = (lane == 0) ? NEGINF : t5n;                                          \
  }

  float t6 = __shfl_up(a6v, 1, 64);
  float t5 = __shfl_up(a5v, 1, 64);
  if (lane == 0) { t6 = NEGINF; t5 = NEGINF; }

  int tt0 = 1;
  for (; tt0 + 8 <= T; tt0 += 8) {
    if (tt0 >= L && tt0 + 7 <= T - L) {
      BODY2(0, 1, 0, STF)  BODY2(2, 3, 1, STF)
      BODY2(4, 5, 2, STF)  BODY2(6, 7, 3, STF)
    } else if (tt0 < L) {           // head: only s<=hi can bind (t<=T-L)
      BODY2(0, 1, 0, STS_HI) BODY2(2, 3, 1, STS_HI)
      BODY2(4, 5, 2, STS_HI) BODY2(6, 7, 3, STS_HI)
    } else {                        // tail blocks: only s>=lo can bind
      BODY2(0, 1, 0, STS_LO) BODY2(2, 3, 1, STS_LO)
      BODY2(4, 5, 2, STS_LO) BODY2(6, 7, 3, STS_LO)
    }
  }
#undef BODY2

  // Drain the ring before the cold tail / backtrace.
  asm volatile("s_waitcnt vmcnt(0) lgkmcnt(0)" ::: "memory");
  __builtin_amdgcn_sched_barrier(0);
  asm volatile("" :: "v"(rq0), "v"(rq1), "v"(rq2), "v"(rq3));
  asm volatile("" :: "v"(rq4), "v"(rq5), "v"(rq6), "v"(rq7));
  asm volatile("" :: "v"(rb0), "v"(rb1), "v"(rb2), "v"(rb3));
  asm volatile("" :: "v"(rb4), "v"(rb5), "v"(rb6), "v"(rb7));

  // Cold tail: remaining steps (<=7), plain loads, lo-side feasibility
  // (t > T-L here since T-L >= 8 and tail starts past the last full block).
  {
    unsigned pendpk = 0;
    for (int t = tt0; t < T; ++t) {
      f32x4 oc = *reinterpret_cast<const f32x4*>(lpq + (size_t)t * 256 +
                                                 lane * 4);
      float bl = blk[t];
      int lo1 = 2 * (L - T + t) - i0;
      int hi1 = 2 * t - i0;
      (void)hi1;
      unsigned pack = 0;
      float m0, m1, m2, m3, m4, m5, m6;
      STS_LO(5, a5v, a4v, a3v, oc.z, bl, m5, pack, lo1, hi1)
      STS_LO(6, a6v, a5v, a4v, oc.w, bl, m6, pack, lo1, hi1)
      float t6m = dpp_wave_shr1(m6);
      float t5m = dpp_wave_shr1(m5);
      STS_LO(0, a0v, t6, t5, oc.x, bl, m0, pack, lo1, hi1)
      STS_LO(1, a1v, a0v, t6, oc.x, bl, m1, pack, lo1, hi1)
      STS_LO(2, a2v, a1v, a0v, oc.y, bl, m2, pack, lo1, hi1)
      STS_LO(3, a3v, a2v, a1v, oc.y, bl, m3, pack, lo1, hi1)
      STS_LO(4, a4v, a3v, a2v, oc.z, bl, m4, pack, lo1, hi1)
      int bi = (t - 1) >> 1, sub = (t - 1) & 1;
      if (sub == 0) pendpk = pack; else pendpk |= pack << 14;
      if (sub == 1 || t == T - 1) offu[(size_t)bi * 64 + lane] = pendpk;
      a0v = m0; a1v = m1; a2v = m2; a3v = m3; a4v = m4; a5v = m5; a6v = m6;
      t6 = (lane == 0) ? NEGINF : t6m;
      t5 = (lane == 0) ? NEGINF : t5m;
    }
  }
#undef STS_LO
#undef STS_HI
#undef STF
#undef LOADQ
#undef LOADB

  // Final-state values (state i -> lane i/7, slot i%7).
  int iN1 = N - 1, iN2 = N - 2;
  auto pick = [&](int sIdx) {
    float r = a0v;
    r = (sIdx == 1) ? a1v : r;
    r = (sIdx == 2) ? a2v : r;
    r = (sIdx == 3) ? a3v : r;
    r = (sIdx == 4) ? a4v : r;
    r = (sIdx == 5) ? a5v : r;
    r = (sIdx == 6) ? a6v : r;
    return r;
  };
  float vlast = __shfl(pick(iN1 % 7), iN1 / 7, 64);
  float vprev = __shfl(pick(iN2 % 7), iN2 / 7, 64);
  bool use_last = vlast > vprev;
  int pre = use_last ? iN1 : iN2;

  float al[4] = {0.f, 0.f, 0.f, 0.f};
  {
    int lbl = L - 1; int rr = lbl >> 6, ln = lbl & 63;
#pragma unroll
    for (int r = 0; r < 4; ++r)
      if (!use_last && rr == r && lane == ln) al[r] = (float)T;
  }

  // Backtrace from LDS offrow (u32 rows of 64). Named scalars only.
  const unsigned* ob = (const unsigned*)smemf;
  int t = T - 1;
  int g = pre / 7, mm = pre - g * 7;

#define CANDS(J, WA, WB, WC, GMV, THREE)                                      \
  {                                                                           \
    int lo = pcur - 2 * (J); if (lo < 0) lo = 0;                              \
    GMV = lo / 7;                                                             \
    int jr = ((J) < K) ? (J) : 0;                                             \
    const unsigned* rp = ob + (size_t)((t - 1 - jr) >> 1) * 64;               \
    WA = rp[GMV]; WB = rp[GMV + 1];                                           \
    if (THREE) WC = rp[GMV + 2]; else WC = WB;                                \
  }

#define DEC(J, WA, WB, WC, GMV)                                               \
  if ((J) < K) {                                                              \
    int gi = g - GMV;                                                         \
    unsigned w = (gi == 0) ? (WA) : ((gi == 1) ? (WB) : (WC));                \
    int sub = (t - 1 - (J)) & 1;                                              \
    unsigned off = (w >> (14 * sub + 2 * mm)) & 3u;                           \
    mm -= (int)off;                                                           \
    bool bor = mm < 0;                                                        \
    g = bor ? (g - 1) : g;                                                    \
    mm = bor ? (mm + 7) : mm;                                                 \
    int cur = 7 * g + mm;                                                     \
    if (cur & 1) {                                                            \
      int lbl = cur >> 1; int rr = lbl >> 6, ln = lbl & 63;                   \
      if (rr == 0 && lane == ln) al[0] = (float)(t - (J));                    \
      if (rr == 1 && lane == ln) al[1] = (float)(t - (J));                    \
      if (rr == 2 && lane == ln) al[2] = (float)(t - (J));                    \
      if (rr == 3 && lane == ln) al[3] = (float)(t - (J));                    \
    }                                                                         \
  }

  while (t >= 1) {
    int K = (t < 7) ? t : 7;
    int pcur = 7 * g + mm;
    unsigned w0 = ob[(size_t)((t - 1) >> 1) * 64 + g];
    unsigned w1a, w1b, w1c, w2a, w2b, w2c, w3a, w3b, w3c;
    unsigned w4a, w4b, w4c, w5a, w5b, w5c, w6a, w6b, w6c;
    int gm1, gm2, gm3, gm4, gm5, gm6;
    CANDS(1, w1a, w1b, w1c, gm1, 0)
    CANDS(2, w2a, w2b, w2c, gm2, 0)
    CANDS(3, w3a, w3b, w3c, gm3, 0)
    CANDS(4, w4a, w4b, w4c, gm4, 1)
    CANDS(5, w5a, w5b, w5c, gm5, 1)
    CANDS(6, w6a, w6b, w6c, gm6, 1)
    int gm0 = g;
    DEC(0, w0, w0, w0, gm0)
    DEC(1, w1a, w1b, w1c, gm1)
    DEC(2, w2a, w2b, w2c, gm2)
    DEC(3, w3a, w3b, w3c, gm3)
    DEC(4, w4a, w4b, w4c, gm4)
    DEC(5, w5a, w5b, w5c, gm5)
    DEC(6, w6a, w6b, w6c, gm6)
    t -= K;
  }
#undef DEC
#undef CANDS

#pragma unroll
  for (int r = 0; r < 4; ++r) {
    int l = lane + 64 * r;
    if (l < L) ali[(size_t)b * L + l] = al[r];
  }
}

// ---------------------------------------------------------------------------
// Kernel C: one wave per (b,layer,o<L) row: dot(ali_out_row, pos) - ali,
// masked, squared; 4 rows/block -> per-block partial sum.
// ---------------------------------------------------------------------------
__global__ __launch_bounds__(256) void kC_rows(
    const float* __restrict__ ali_out, const float* __restrict__ ali,
    const int* __restrict__ ali_beg, float* __restrict__ partials,
    int B, int layers, int L, int T)
{
  __shared__ float ps[4];
  int wid = threadIdx.x >> 6, lane = threadIdx.x & 63;
  int row = blockIdx.x * 4 + wid;
  int nrows = B * layers * L;
  float val = 0.f;
  if (row < nrows) {
    int o = row % L;
    int bl = row / L;
    int layer = bl % layers;
    int b = bl / layers;
    const float* x = ali_out + ((size_t)(b * layers + layer) * (L + 1) + o) * T;
    float s = 0.f;
    if ((T & 3) == 0) {
      int nf4 = T >> 2;
      for (int k = lane; k < nf4; k += 64) {
        float4 v = reinterpret_cast<const float4*>(x)[k];
        float base = (float)(4 * k);
        s += v.x * (base + 1.f) + v.y * (base + 2.f) +
             v.z * (base + 3.f) + v.w * (base + 4.f);
      }
    } else {
      for (int k = lane; k < T; k += 64) s += x[k] * (float)(k + 1);
    }
    s = wave_sum_f(s);
    int cnt = 0;
    for (int l = lane; l < L; l += 64)
      cnt += (ali_beg[(size_t)b * L + l] != -1) ? 1 : 0;
    cnt = wave_sum_i(cnt);
    if (lane == 0) {
      float lat = (o >= cnt) ? 0.f : (s - ali[(size_t)b * L + o]);
      val = lat * lat;
    }
  }
  if (lane == 0) ps[wid] = val;
  __syncthreads();
  if (threadIdx.x == 0) partials[blockIdx.x] = ps[0] + ps[1] + ps[2] + ps[3];
}

// ---------------------------------------------------------------------------
// Kernel D: reduce partials, compute total = layers * sum(ylen), write scalar.
// ---------------------------------------------------------------------------
__global__ __launch_bounds__(256) void kD_final(
    const float* __restrict__ partials, int nparts,
    const int* __restrict__ ali_beg, int BL, int layers, int T,
    float* __restrict__ out)
{
  __shared__ float wred[4];
  __shared__ int wcnt[4];
  int tid = threadIdx.x, w = tid >> 6;
  float s = 0.f;
  for (int k = tid; k < nparts; k += 256) s += partials[k];
  s = wave_sum_f(s);
  int c = 0;
  for (int k = tid; k < BL; k += 256) c += (ali_beg[k] != -1) ? 1 : 0;
  c = wave_sum_i(c);
  if ((tid & 63) == 0) { wred[w] = s; wcnt[w] = c; }
  __syncthreads();
  if (tid == 0) {
    float ss = wred[0] + wred[1] + wred[2] + wred[3];
    float total = (float)(wcnt[0] + wcnt[1] + wcnt[2] + wcnt[3]) * (float)layers;
    out[0] = ss / total / (float)T;
  }
}

// Copy ctc_label into the segment after blankArr so kB reads labels from the
// same base pointer (no extra kernel param plumbing).
__global__ __launch_bounds__(256) void kL_copy(
    const int* __restrict__ src, int* __restrict__ dst, int n)
{
  int i = blockIdx.x * 256 + threadIdx.x;
  if (i < n) dst[i] = src[i];
}

extern "C" void kernel_launch(void* const* d_in, const int* in_sizes, int n_in,
                              void* d_out, int out_size, void* d_ws, size_t ws_size,
                              hipStream_t stream)
{
  const float* ali_out   = (const float*)d_in[0];
  const int*   ali_beg   = (const int*)d_in[1];
  // d_in[2] ali_end, d_in[3] enc_mask, d_in[6] ctc_len: unused by reference math
  const float* ctc_out   = (const float*)d_in[4];
  const int*   ctc_label = (const int*)d_in[5];

  int B = in_sizes[6];
  int L = in_sizes[1] / B;
  int T = in_sizes[3] / B;
  int V = (int)((long long)in_sizes[4] / ((long long)B * T));
  int layers = (int)((long long)in_sizes[0] / ((long long)B * (L + 1) * T));

  int TPAD = T + 16;                 // ring over-read pad

  // workspace layout
  float* lpsQuad = (float*)d_ws;                            // B*TPAD*256
  float* blankArr = lpsQuad + (size_t)B * TPAD * 256;       // B*TPAD
  int* labCopy = (int*)(blankArr + (size_t)B * TPAD);       // B*L (after blank)
  float* ali = (float*)(labCopy + (size_t)B * L);           // B*L
  float* partials = ali + (size_t)B * L;                    // gridC
  int nrows = B * layers * L;
  int gridC = (nrows + 3) / 4;

  // L-copy: labels adjacent to blankArr for kB's single-base access
  hipLaunchKernelGGL(kL_copy, dim3((B * L + 255) / 256), dim3(256), 0, stream,
                     ctc_label, labCopy, B * L);

  // A: logsumexp + per-lane pre-gather
  size_t shA = (size_t)V * sizeof(float);
  hipLaunchKernelGGL(kA_lse_gather, dim3(B * T), dim3(256), shA, stream,
                     ctc_out, ctc_label, lpsQuad, blankArr, B, T, V, L, TPAD);

  // B: Viterbi forward + backtrace (one wave per batch item)
  size_t shB = (size_t)(T >> 1) * 256;
  hipFuncSetAttribute(reinterpret_cast<const void*>(kB_viterbi),
                      hipFuncAttributeMaxDynamicSharedMemorySize, (int)shB);
  hipLaunchKernelGGL(kB_viterbi, dim3(B), dim3(64), shB, stream,
                     lpsQuad, blankArr, ali, B, T, L, TPAD);

  // C: expected-position rows + squared residual partials
  hipLaunchKernelGGL(kC_rows, dim3(gridC), dim3(256), 0, stream,
                     ali_out, ali, ali_beg, partials, B, layers, L, T);

  // D: finalize scalar
  hipLaunchKernelGGL(kD_final, dim3(1), dim3(256), 0, stream,
                     partials, gridC, ali_beg, B * L, layers, T, (float*)d_out);
}